// Round 3
// baseline (499.556 us; speedup 1.0000x reference)
//
#include <hip/hip_runtime.h>
#include <hip/hip_bf16.h>
#include <cstdint>

#define B_N 65536
#define F_N 64
#define L_N 32
#define E_N 512
// K = F*L = 2048, k-octs = 256

typedef short bf16x8 __attribute__((ext_vector_type(8)));
typedef float f32x4 __attribute__((ext_vector_type(4)));

// exact GELU via Abramowitz-Stegun 7.1.26 erf (|abs err| <= 1.5e-7)
__device__ __forceinline__ float gelu_exact(float v) {
  float z  = v * 0.7071067811865476f;
  float az = fabsf(z);
  float t  = __builtin_amdgcn_rcpf(fmaf(0.3275911f, az, 1.0f));
  float p  = t * fmaf(t, fmaf(t, fmaf(t, fmaf(t, 1.061405429f, -1.453152027f),
                                      1.421413741f), -0.284496736f), 0.254829592f);
  float e    = __expf(-z * z);
  float erfa = fmaf(-p, e, 1.0f);
  float er   = (z < 0.0f) ? -erfa : erfa;
  return v * fmaf(0.5f, er, 0.5f);
}

// ---------------- prep: softmax(w_raw), wb2 = w @ b2, w -> d_out tail ------
__global__ __launch_bounds__(128) void k_prep(const float* __restrict__ w_raw,
                                              const float* __restrict__ b2,
                                              float* __restrict__ w_s,
                                              float* __restrict__ wb2,
                                              float* __restrict__ out_tail) {
  int tid = threadIdx.x;
  float m = -1e30f;
  for (int i = 0; i < F_N; i++) m = fmaxf(m, w_raw[i]);
  float s = 0.f;
  for (int i = 0; i < F_N; i++) s += expf(w_raw[i] - m);
  float inv_s = 1.0f / s;
  if (blockIdx.x == 0 && tid < F_N) {
    float wv = expf(w_raw[tid] - m) * inv_s;
    w_s[tid] = wv;
    out_tail[tid] = wv;
  }
  int e = blockIdx.x * 128 + tid;
  float a = 0.f;
  for (int f = 0; f < F_N; f++)
    a = fmaf(expf(w_raw[f] - m) * inv_s, b2[f * E_N + e], a);
  wb2[e] = a;
}

// ---------------- W1 -> bf16 MFMA-A-fragment table ------------------------
// W1T[(f*2+jt)*64 + lane] = 8 bf16 { W1[f][quad*8+jj][jt*16+r16], jj=0..7 }
__global__ __launch_bounds__(64) void k_w1t(const float* __restrict__ W1,
                                            uint4* __restrict__ W1T) {
  int f = blockIdx.x;
  int lane = threadIdx.x;
  int quad = lane >> 4, r16 = lane & 15;
#pragma unroll
  for (int jt = 0; jt < 2; jt++) {
    union { __hip_bfloat162 p[4]; uint4 u; } pk;
#pragma unroll
    for (int d = 0; d < 4; d++) {
      float lo = W1[f * 1024 + (quad * 8 + 2 * d) * 32 + jt * 16 + r16];
      float hi = W1[f * 1024 + (quad * 8 + 2 * d + 1) * 32 + jt * 16 + r16];
      pk.p[d] = __float22bfloat162_rn(make_float2(lo, hi));
    }
    W1T[(f * 2 + jt) * 64 + lane] = pk.u;
  }
}

// ---------------- W2 [2048][512] fp32 -> blocked bf16 [k_oct][e][8] --------
__global__ __launch_bounds__(256) void k_w2t(const float* __restrict__ W2,
                                             uint4* __restrict__ W2T) {
  __shared__ float ls[64 * 65];
  int kt = blockIdx.x >> 3, et = blockIdx.x & 7;
  int k0 = kt * 64, e0 = et * 64;
  int tid = threadIdx.x;
#pragma unroll
  for (int i = 0; i < 16; i++) {
    int idx = i * 256 + tid;
    int r = idx >> 6, c = idx & 63;
    ls[r * 65 + c] = W2[(size_t)(k0 + r) * E_N + e0 + c];
  }
  __syncthreads();
#pragma unroll
  for (int i = 0; i < 2; i++) {
    int t = i * 256 + tid;
    int ko = t >> 6, e = t & 63;
    union { __hip_bfloat162 p[4]; uint4 u; } pk;
#pragma unroll
    for (int d = 0; d < 4; d++)
      pk.p[d] = __float22bfloat162_rn(make_float2(ls[(ko * 8 + 2 * d) * 65 + e],
                                                  ls[(ko * 8 + 2 * d + 1) * 65 + e]));
    W2T[(size_t)(kt * 8 + ko) * E_N + e0 + e] = pk.u;
  }
}

// ---------------- FUSED: enc->W1->LN->GELU->*w (LDS) -> GEMM vs W2T -------
// block: 64 b-rows, 512 threads (8 waves). 8 chunks of 8 features (K=256).
// enc phase: wave w computes f = c*8+w into LDS hw (blocked [ko][b][8bf16]).
// gemm phase: wave w owns n-strip of 64; acc 4x4 16x16 tiles (64 fp32/lane).
__global__ __launch_bounds__(512, 4) void k_fused(const float* __restrict__ bf,
                                                  const uint4* __restrict__ W1T,
                                                  const float* __restrict__ b1,
                                                  const float* __restrict__ gamma,
                                                  const float* __restrict__ beta,
                                                  const float* __restrict__ w_s,
                                                  const uint4* __restrict__ W2T,
                                                  const float* __restrict__ wb2,
                                                  float* __restrict__ out) {
  __shared__ float xs[64 * 65];   // x transposed [f][b], pad for banks
  __shared__ uint4 hw[32 * 64];   // Hw chunk, blocked [ko_local 0..31][b 0..63]
  int tid = threadIdx.x;
  int b0 = blockIdx.x * 64;
  // stage x tile: global coalesced, LDS write 2-way (free)
#pragma unroll
  for (int i = 0; i < 8; i++) {
    int idx = i * 512 + tid;
    xs[(idx & 63) * 65 + (idx >> 6)] = bf[(size_t)b0 * F_N + idx];
  }
  int wave = tid >> 6, lane = tid & 63;
  int quad = lane >> 4, r16 = lane & 15;
  // enc lane constants: k = quad*8+jj ; cos = sin(t + 0.25 rev)
  float c_t   = 0.015915494309189535f * ((quad & 1) ? 256.0f : 1.0f);
  float phase = (quad >= 2) ? 0.25f : 0.0f;
  f32x4 zero = {0.f, 0.f, 0.f, 0.f};

  f32x4 acc[4][4];
#pragma unroll
  for (int i = 0; i < 4; i++)
#pragma unroll
    for (int j = 0; j < 4; j++) acc[i][j] = zero;

  int n_base = wave * 64;
  __syncthreads();

  for (int c = 0; c < 8; ++c) {
    int f = c * 8 + wave;
    // ---- enc phase: this wave's feature f -> hw[wave*4 .. wave*4+3] ----
    bf16x8 a0 = __builtin_bit_cast(bf16x8, W1T[(f * 2 + 0) * 64 + lane]);
    bf16x8 a1 = __builtin_bit_cast(bf16x8, W1T[(f * 2 + 1) * 64 + lane]);
    float wf = w_s[f];
    f32x4 c0, c1;  // seed C with b1 (row = j = jt*16 + quad*4 + rr)
#pragma unroll
    for (int rr = 0; rr < 4; rr++) {
      c0[rr] = b1[f * 32 + quad * 4 + rr];
      c1[rr] = b1[f * 32 + 16 + quad * 4 + rr];
    }
    if (c) __syncthreads();  // prev gemm phase done reading hw

#pragma unroll
    for (int bt = 0; bt < 4; bt++) {
      float x = xs[f * 65 + bt * 16 + r16];
      float v[8];
      float t = x * c_t;
#pragma unroll
      for (int jj = 0; jj < 8; jj++) {
        float y = t + phase;
        y = y - floorf(y);
        v[jj] = __builtin_amdgcn_sinf(y);
        t = t + t;
      }
      union { __hip_bfloat162 p[4]; bf16x8 r; } pk;
#pragma unroll
      for (int d = 0; d < 4; d++)
        pk.p[d] = __float22bfloat162_rn(make_float2(v[2 * d], v[2 * d + 1]));
      f32x4 e0 = __builtin_amdgcn_mfma_f32_16x16x32_bf16(a0, pk.r, c0, 0, 0, 0);
      f32x4 e1 = __builtin_amdgcn_mfma_f32_16x16x32_bf16(a1, pk.r, c1, 0, 0, 0);
      float h[8];
#pragma unroll
      for (int rr = 0; rr < 4; rr++) { h[rr] = e0[rr]; h[4 + rr] = e1[rr]; }
      // LN over 32 j (lane holds 8; butterfly over quads)
      float s = 0.f;
#pragma unroll
      for (int q = 0; q < 8; q++) s += h[q];
      s += __shfl_xor(s, 16);
      s += __shfl_xor(s, 32);
      float mu = s * (1.0f / 32.0f);
      float var = 0.f;
#pragma unroll
      for (int q = 0; q < 8; q++) { h[q] -= mu; var = fmaf(h[q], h[q], var); }
      var += __shfl_xor(var, 16);
      var += __shfl_xor(var, 32);
      float rs = __builtin_amdgcn_rsqf(fmaf(var, (1.0f / 32.0f), 1e-5f));
#pragma unroll
      for (int q = 0; q < 8; q++) {
        int jt = q >> 2, rr = q & 3;
        int idx = f * 32 + jt * 16 + quad * 4 + rr;
        float hn = fmaf(h[q] * rs, gamma[idx], beta[idx]);
        h[q] = gelu_exact(hn) * wf;
      }
      int b_local = bt * 16 + r16;
#pragma unroll
      for (int jt = 0; jt < 2; jt++) {
        union { __hip_bfloat162 p[2]; uint2 u; } pw;
        pw.p[0] = __float22bfloat162_rn(make_float2(h[jt * 4 + 0], h[jt * 4 + 1]));
        pw.p[1] = __float22bfloat162_rn(make_float2(h[jt * 4 + 2], h[jt * 4 + 3]));
        int ko_local = wave * 4 + jt * 2 + (quad >> 1);
        *(uint2*)((char*)hw + ((size_t)(ko_local * 64 + b_local) * 16 +
                               (quad & 1) * 8)) = pw.u;
      }
    }
    __syncthreads();

    // ---- gemm phase: acc += hw(64b x 256k) @ W2T(256k x n-strip 64) ----
#pragma unroll
    for (int s = 0; s < 8; s++) {
      bf16x8 af[4], bfr[4];
#pragma unroll
      for (int mt = 0; mt < 4; mt++)
        af[mt] = __builtin_bit_cast(bf16x8, hw[(s * 4 + quad) * 64 + mt * 16 + r16]);
#pragma unroll
      for (int nt = 0; nt < 4; nt++)
        bfr[nt] = __builtin_bit_cast(
            bf16x8, W2T[(size_t)(c * 32 + s * 4 + quad) * E_N + n_base + nt * 16 + r16]);
#pragma unroll
      for (int mt = 0; mt < 4; mt++)
#pragma unroll
        for (int nt = 0; nt < 4; nt++)
          acc[mt][nt] = __builtin_amdgcn_mfma_f32_16x16x32_bf16(af[mt], bfr[nt],
                                                                acc[mt][nt], 0, 0, 0);
    }
  }

  // epilogue: C/D layout col=n (r16), row=m (quad*4+rr); add wb2 bias
#pragma unroll
  for (int nt = 0; nt < 4; nt++) {
    int n = n_base + nt * 16 + r16;
    float bias = wb2[n];
#pragma unroll
    for (int mt = 0; mt < 4; mt++) {
#pragma unroll
      for (int rr = 0; rr < 4; rr++) {
        int m = b0 + mt * 16 + quad * 4 + rr;
        out[(size_t)m * E_N + n] = acc[mt][nt][rr] + bias;
      }
    }
  }
}

// ---------------- correctness fallback if ws_size too small ----------------
__global__ __launch_bounds__(64) void k_naive(const float* __restrict__ bf,
                                              const float* __restrict__ w_raw,
                                              const float* __restrict__ W1,
                                              const float* __restrict__ b1,
                                              const float* __restrict__ gamma,
                                              const float* __restrict__ beta,
                                              const float* __restrict__ W2,
                                              const float* __restrict__ b2,
                                              float* __restrict__ out) {
  int b = blockIdx.x;
  int lane = threadIdx.x;
  float m = -1e30f;
  for (int i = 0; i < F_N; i++) m = fmaxf(m, w_raw[i]);
  float s = 0.f;
  for (int i = 0; i < F_N; i++) s += expf(w_raw[i] - m);
  float inv_s = 1.0f / s;
  float acc[8];
#pragma unroll
  for (int r = 0; r < 8; r++) acc[r] = 0.f;
  __shared__ float hs[32];
  for (int f = 0; f < F_N; f++) {
    float wf = expf(w_raw[f] - m) * inv_s;
    __syncthreads();
    if (lane < 32) {
      float x = bf[(size_t)b * F_N + f];
      float t = x * 0.015915494309189535f;
      float h = b1[f * 32 + lane];
#pragma unroll
      for (int i = 0; i < 16; i++) {
        float y = t - floorf(t);
        h = fmaf(__builtin_amdgcn_sinf(y), W1[f * 1024 + i * 32 + lane], h);
        h = fmaf(__builtin_amdgcn_cosf(y), W1[f * 1024 + 512 + i * 32 + lane], h);
        t = t + t;
      }
      float sum = h;
#pragma unroll
      for (int msk = 1; msk < 32; msk <<= 1) sum += __shfl_xor(sum, msk, 64);
      float mu = sum * (1.0f / 32.0f);
      float d = h - mu;
      float sq = d * d;
#pragma unroll
      for (int msk = 1; msk < 32; msk <<= 1) sq += __shfl_xor(sq, msk, 64);
      float rs = __builtin_amdgcn_rsqf(fmaf(sq, (1.0f / 32.0f), 1e-5f));
      float hn = fmaf(d * rs, gamma[f * 32 + lane], beta[f * 32 + lane]);
      hs[lane] = gelu_exact(hn) * wf;
    }
    __syncthreads();
#pragma unroll
    for (int r = 0; r < 8; r++) {
      int e = r * 64 + lane;
      float a = fmaf(wf, b2[f * E_N + e], acc[r]);
      for (int j = 0; j < 32; j++)
        a = fmaf(hs[j], W2[(size_t)(f * 32 + j) * E_N + e], a);
      acc[r] = a;
    }
  }
#pragma unroll
  for (int r = 0; r < 8; r++) out[(size_t)b * E_N + r * 64 + lane] = acc[r];
  if (b == 0) out[(size_t)B_N * E_N + lane] = expf(w_raw[lane] - m) * inv_s;
}

extern "C" void kernel_launch(void* const* d_in, const int* in_sizes, int n_in,
                              void* d_out, int out_size, void* d_ws, size_t ws_size,
                              hipStream_t stream) {
  const float* bf    = (const float*)d_in[0];
  const float* w_raw = (const float*)d_in[1];
  const float* W1    = (const float*)d_in[2];
  const float* b1    = (const float*)d_in[3];
  const float* gamma = (const float*)d_in[4];
  const float* beta  = (const float*)d_in[5];
  const float* W2    = (const float*)d_in[6];
  const float* b2    = (const float*)d_in[7];
  float* out = (float*)d_out;

  const size_t W2T_BYTES = (size_t)256 * E_N * 16;  // 2 MB
  const size_t W_OFF     = W2T_BYTES;
  const size_t WB2_OFF   = W_OFF + 256;
  const size_t W1T_OFF   = WB2_OFF + 4096;
  const size_t NEED      = W1T_OFF + 131072;

  if (ws_size < NEED) {  // deterministic fallback (correctness insurance)
    k_naive<<<B_N, 64, 0, stream>>>(bf, w_raw, W1, b1, gamma, beta, W2, b2, out);
    return;
  }
  char* ws = (char*)d_ws;
  uint4* W2T = (uint4*)ws;
  float* w_s = (float*)(ws + W_OFF);
  float* wb2 = (float*)(ws + WB2_OFF);
  uint4* W1T = (uint4*)(ws + W1T_OFF);

  k_prep<<<4, 128, 0, stream>>>(w_raw, b2, w_s, wb2, out + (size_t)B_N * E_N);
  k_w1t<<<64, 64, 0, stream>>>(W1, W1T);
  k_w2t<<<256, 256, 0, stream>>>(W2, W2T);
  k_fused<<<B_N / 64, 512, 0, stream>>>(bf, W1T, b1, gamma, beta, w_s, W2T, wb2, out);
}

// Round 4
// 432.630 us; speedup vs baseline: 1.1547x; 1.1547x over previous
//
#include <hip/hip_runtime.h>
#include <hip/hip_bf16.h>
#include <cstdint>

#define B_N 65536
#define F_N 64
#define L_N 32
#define E_N 512
// K = F*L = 2048, k-octs = 256

typedef short bf16x8 __attribute__((ext_vector_type(8)));
typedef float f32x4 __attribute__((ext_vector_type(4)));

// exact GELU via Abramowitz-Stegun 7.1.26 erf (|abs err| <= 1.5e-7)
__device__ __forceinline__ float gelu_exact(float v) {
  float z  = v * 0.7071067811865476f;
  float az = fabsf(z);
  float t  = __builtin_amdgcn_rcpf(fmaf(0.3275911f, az, 1.0f));
  float p  = t * fmaf(t, fmaf(t, fmaf(t, fmaf(t, 1.061405429f, -1.453152027f),
                                      1.421413741f), -0.284496736f), 0.254829592f);
  float e    = __expf(-z * z);
  float erfa = fmaf(-p, e, 1.0f);
  float er   = (z < 0.0f) ? -erfa : erfa;
  return v * fmaf(0.5f, er, 0.5f);
}

// ---------------- prep: softmax(w_raw), wb2 = w @ b2, w -> d_out tail ------
__global__ __launch_bounds__(128) void k_prep(const float* __restrict__ w_raw,
                                              const float* __restrict__ b2,
                                              float* __restrict__ w_s,
                                              float* __restrict__ wb2,
                                              float* __restrict__ out_tail) {
  int tid = threadIdx.x;
  float m = -1e30f;
  for (int i = 0; i < F_N; i++) m = fmaxf(m, w_raw[i]);
  float s = 0.f;
  for (int i = 0; i < F_N; i++) s += expf(w_raw[i] - m);
  float inv_s = 1.0f / s;
  if (blockIdx.x == 0 && tid < F_N) {
    float wv = expf(w_raw[tid] - m) * inv_s;
    w_s[tid] = wv;
    out_tail[tid] = wv;
  }
  int e = blockIdx.x * 128 + tid;
  float a = 0.f;
  for (int f = 0; f < F_N; f++)
    a = fmaf(expf(w_raw[f] - m) * inv_s, b2[f * E_N + e], a);
  wb2[e] = a;
}

// ---------------- W1 -> bf16 MFMA-A-fragment table ------------------------
// W1T[(f*2+jt)*64 + lane] = 8 bf16 { W1[f][quad*8+jj][jt*16+r16], jj=0..7 }
__global__ __launch_bounds__(64) void k_w1t(const float* __restrict__ W1,
                                            uint4* __restrict__ W1T) {
  int f = blockIdx.x;
  int lane = threadIdx.x;
  int quad = lane >> 4, r16 = lane & 15;
#pragma unroll
  for (int jt = 0; jt < 2; jt++) {
    union { __hip_bfloat162 p[4]; uint4 u; } pk;
#pragma unroll
    for (int d = 0; d < 4; d++) {
      float lo = W1[f * 1024 + (quad * 8 + 2 * d) * 32 + jt * 16 + r16];
      float hi = W1[f * 1024 + (quad * 8 + 2 * d + 1) * 32 + jt * 16 + r16];
      pk.p[d] = __float22bfloat162_rn(make_float2(lo, hi));
    }
    W1T[(f * 2 + jt) * 64 + lane] = pk.u;
  }
}

// ---------------- W2 [2048][512] fp32 -> blocked bf16 [k_oct][e][8] --------
__global__ __launch_bounds__(256) void k_w2t(const float* __restrict__ W2,
                                             uint4* __restrict__ W2T) {
  __shared__ float ls[64 * 65];
  int kt = blockIdx.x >> 3, et = blockIdx.x & 7;
  int k0 = kt * 64, e0 = et * 64;
  int tid = threadIdx.x;
#pragma unroll
  for (int i = 0; i < 16; i++) {
    int idx = i * 256 + tid;
    int r = idx >> 6, c = idx & 63;
    ls[r * 65 + c] = W2[(size_t)(k0 + r) * E_N + e0 + c];
  }
  __syncthreads();
#pragma unroll
  for (int i = 0; i < 2; i++) {
    int t = i * 256 + tid;
    int ko = t >> 6, e = t & 63;
    union { __hip_bfloat162 p[4]; uint4 u; } pk;
#pragma unroll
    for (int d = 0; d < 4; d++)
      pk.p[d] = __float22bfloat162_rn(make_float2(ls[(ko * 8 + 2 * d) * 65 + e],
                                                  ls[(ko * 8 + 2 * d + 1) * 65 + e]));
    W2T[(size_t)(kt * 8 + ko) * E_N + e0 + e] = pk.u;
  }
}

// ---------------- FUSED: enc->W1->LN->GELU->*w (LDS) -> GEMM vs W2T -------
// block: 64 b-rows, 512 threads (8 waves). 8 chunks of 8 features (K=256).
// enc phase: wave w computes f = c*8+w into LDS hw (blocked [ko][b][8bf16]).
// gemm phase: wave w owns n-strip of 64; acc 4x4 16x16 tiles (64 fp32/lane).
// launch_bounds (512,2): VGPR cap 256 — R3's (512,4) cap of 128 spilled the
// 64-reg accumulator to scratch (FETCH 419MB/WRITE 646MB pathology).
__global__ __launch_bounds__(512, 2) void k_fused(const float* __restrict__ bf,
                                                  const uint4* __restrict__ W1T,
                                                  const float* __restrict__ b1,
                                                  const float* __restrict__ gamma,
                                                  const float* __restrict__ beta,
                                                  const float* __restrict__ w_s,
                                                  const uint4* __restrict__ W2T,
                                                  const float* __restrict__ wb2,
                                                  float* __restrict__ out) {
  __shared__ float xs[64 * 65];   // x transposed [f][b], pad for banks
  __shared__ uint4 hw[32 * 64];   // Hw chunk, blocked [ko_local 0..31][b 0..63]
  int tid = threadIdx.x;
  int b0 = blockIdx.x * 64;
  // stage x tile: global coalesced, LDS write 2-way (free)
#pragma unroll
  for (int i = 0; i < 8; i++) {
    int idx = i * 512 + tid;
    xs[(idx & 63) * 65 + (idx >> 6)] = bf[(size_t)b0 * F_N + idx];
  }
  int wave = tid >> 6, lane = tid & 63;
  int quad = lane >> 4, r16 = lane & 15;
  // enc lane constants: k = quad*8+jj ; cos = sin(t + 0.25 rev)
  float c_t   = 0.015915494309189535f * ((quad & 1) ? 256.0f : 1.0f);
  float phase = (quad >= 2) ? 0.25f : 0.0f;

  f32x4 acc[4][4];
  f32x4 zero = {0.f, 0.f, 0.f, 0.f};
#pragma unroll
  for (int i = 0; i < 4; i++)
#pragma unroll
    for (int j = 0; j < 4; j++) acc[i][j] = zero;

  int n_base = wave * 64;
  __syncthreads();

  for (int c = 0; c < 8; ++c) {
    int f = c * 8 + wave;
    // ---- enc phase: this wave's feature f -> hw[wave*4 .. wave*4+3] ----
    bf16x8 a0 = __builtin_bit_cast(bf16x8, W1T[(f * 2 + 0) * 64 + lane]);
    bf16x8 a1 = __builtin_bit_cast(bf16x8, W1T[(f * 2 + 1) * 64 + lane]);
    float wf = w_s[f];
    f32x4 c0, c1;  // seed C with b1 (row = j = jt*16 + quad*4 + rr)
#pragma unroll
    for (int rr = 0; rr < 4; rr++) {
      c0[rr] = b1[f * 32 + quad * 4 + rr];
      c1[rr] = b1[f * 32 + 16 + quad * 4 + rr];
    }
    if (c) __syncthreads();  // prev gemm phase done reading hw

#pragma unroll
    for (int bt = 0; bt < 4; bt++) {
      float x = xs[f * 65 + bt * 16 + r16];
      float v[8];
      float t = x * c_t;
#pragma unroll
      for (int jj = 0; jj < 8; jj++) {
        float y = t + phase;
        y = y - floorf(y);
        v[jj] = __builtin_amdgcn_sinf(y);
        t = t + t;
      }
      union { __hip_bfloat162 p[4]; bf16x8 r; } pk;
#pragma unroll
      for (int d = 0; d < 4; d++)
        pk.p[d] = __float22bfloat162_rn(make_float2(v[2 * d], v[2 * d + 1]));
      f32x4 e0 = __builtin_amdgcn_mfma_f32_16x16x32_bf16(a0, pk.r, c0, 0, 0, 0);
      f32x4 e1 = __builtin_amdgcn_mfma_f32_16x16x32_bf16(a1, pk.r, c1, 0, 0, 0);
      float h[8];
#pragma unroll
      for (int rr = 0; rr < 4; rr++) { h[rr] = e0[rr]; h[4 + rr] = e1[rr]; }
      // LN over 32 j (lane holds 8; butterfly over quads)
      float s = 0.f;
#pragma unroll
      for (int q = 0; q < 8; q++) s += h[q];
      s += __shfl_xor(s, 16);
      s += __shfl_xor(s, 32);
      float mu = s * (1.0f / 32.0f);
      float var = 0.f;
#pragma unroll
      for (int q = 0; q < 8; q++) { h[q] -= mu; var = fmaf(h[q], h[q], var); }
      var += __shfl_xor(var, 16);
      var += __shfl_xor(var, 32);
      float rs = __builtin_amdgcn_rsqf(fmaf(var, (1.0f / 32.0f), 1e-5f));
#pragma unroll
      for (int q = 0; q < 8; q++) {
        int jt = q >> 2, rr = q & 3;
        int idx = f * 32 + jt * 16 + quad * 4 + rr;
        float hn = fmaf(h[q] * rs, gamma[idx], beta[idx]);
        h[q] = gelu_exact(hn) * wf;
      }
      int b_local = bt * 16 + r16;
#pragma unroll
      for (int jt = 0; jt < 2; jt++) {
        union { __hip_bfloat162 p[2]; uint2 u; } pw;
        pw.p[0] = __float22bfloat162_rn(make_float2(h[jt * 4 + 0], h[jt * 4 + 1]));
        pw.p[1] = __float22bfloat162_rn(make_float2(h[jt * 4 + 2], h[jt * 4 + 3]));
        int ko_local = wave * 4 + jt * 2 + (quad >> 1);
        *(uint2*)((char*)hw + ((size_t)(ko_local * 64 + b_local) * 16 +
                               (quad & 1) * 8)) = pw.u;
      }
    }
    __syncthreads();

    // ---- gemm phase: acc += hw(64b x 256k) @ W2T(256k x n-strip 64) ----
#pragma unroll
    for (int s = 0; s < 8; s++) {
      bf16x8 af[4], bfr[4];
#pragma unroll
      for (int mt = 0; mt < 4; mt++)
        af[mt] = __builtin_bit_cast(bf16x8, hw[(s * 4 + quad) * 64 + mt * 16 + r16]);
#pragma unroll
      for (int nt = 0; nt < 4; nt++)
        bfr[nt] = __builtin_bit_cast(
            bf16x8, W2T[(size_t)(c * 32 + s * 4 + quad) * E_N + n_base + nt * 16 + r16]);
#pragma unroll
      for (int mt = 0; mt < 4; mt++)
#pragma unroll
        for (int nt = 0; nt < 4; nt++)
          acc[mt][nt] = __builtin_amdgcn_mfma_f32_16x16x32_bf16(af[mt], bfr[nt],
                                                                acc[mt][nt], 0, 0, 0);
    }
  }

  // epilogue: C/D layout col=n (r16), row=m (quad*4+rr); add wb2 bias
#pragma unroll
  for (int nt = 0; nt < 4; nt++) {
    int n = n_base + nt * 16 + r16;
    float bias = wb2[n];
#pragma unroll
    for (int mt = 0; mt < 4; mt++) {
#pragma unroll
      for (int rr = 0; rr < 4; rr++) {
        int m = b0 + mt * 16 + quad * 4 + rr;
        out[(size_t)m * E_N + n] = acc[mt][nt][rr] + bias;
      }
    }
  }
}

// ---------------- correctness fallback if ws_size too small ----------------
__global__ __launch_bounds__(64) void k_naive(const float* __restrict__ bf,
                                              const float* __restrict__ w_raw,
                                              const float* __restrict__ W1,
                                              const float* __restrict__ b1,
                                              const float* __restrict__ gamma,
                                              const float* __restrict__ beta,
                                              const float* __restrict__ W2,
                                              const float* __restrict__ b2,
                                              float* __restrict__ out) {
  int b = blockIdx.x;
  int lane = threadIdx.x;
  float m = -1e30f;
  for (int i = 0; i < F_N; i++) m = fmaxf(m, w_raw[i]);
  float s = 0.f;
  for (int i = 0; i < F_N; i++) s += expf(w_raw[i] - m);
  float inv_s = 1.0f / s;
  float acc[8];
#pragma unroll
  for (int r = 0; r < 8; r++) acc[r] = 0.f;
  __shared__ float hs[32];
  for (int f = 0; f < F_N; f++) {
    float wf = expf(w_raw[f] - m) * inv_s;
    __syncthreads();
    if (lane < 32) {
      float x = bf[(size_t)b * F_N + f];
      float t = x * 0.015915494309189535f;
      float h = b1[f * 32 + lane];
#pragma unroll
      for (int i = 0; i < 16; i++) {
        float y = t - floorf(t);
        h = fmaf(__builtin_amdgcn_sinf(y), W1[f * 1024 + i * 32 + lane], h);
        h = fmaf(__builtin_amdgcn_cosf(y), W1[f * 1024 + 512 + i * 32 + lane], h);
        t = t + t;
      }
      float sum = h;
#pragma unroll
      for (int msk = 1; msk < 32; msk <<= 1) sum += __shfl_xor(sum, msk, 64);
      float mu = sum * (1.0f / 32.0f);
      float d = h - mu;
      float sq = d * d;
#pragma unroll
      for (int msk = 1; msk < 32; msk <<= 1) sq += __shfl_xor(sq, msk, 64);
      float rs = __builtin_amdgcn_rsqf(fmaf(sq, (1.0f / 32.0f), 1e-5f));
      float hn = fmaf(d * rs, gamma[f * 32 + lane], beta[f * 32 + lane]);
      hs[lane] = gelu_exact(hn) * wf;
    }
    __syncthreads();
#pragma unroll
    for (int r = 0; r < 8; r++) {
      int e = r * 64 + lane;
      float a = fmaf(wf, b2[f * E_N + e], acc[r]);
      for (int j = 0; j < 32; j++)
        a = fmaf(hs[j], W2[(size_t)(f * 32 + j) * E_N + e], a);
      acc[r] = a;
    }
  }
#pragma unroll
  for (int r = 0; r < 8; r++) out[(size_t)b * E_N + r * 64 + lane] = acc[r];
  if (b == 0) out[(size_t)B_N * E_N + lane] = expf(w_raw[lane] - m) * inv_s;
}

extern "C" void kernel_launch(void* const* d_in, const int* in_sizes, int n_in,
                              void* d_out, int out_size, void* d_ws, size_t ws_size,
                              hipStream_t stream) {
  const float* bf    = (const float*)d_in[0];
  const float* w_raw = (const float*)d_in[1];
  const float* W1    = (const float*)d_in[2];
  const float* b1    = (const float*)d_in[3];
  const float* gamma = (const float*)d_in[4];
  const float* beta  = (const float*)d_in[5];
  const float* W2    = (const float*)d_in[6];
  const float* b2    = (const float*)d_in[7];
  float* out = (float*)d_out;

  const size_t W2T_BYTES = (size_t)256 * E_N * 16;  // 2 MB
  const size_t W_OFF     = W2T_BYTES;
  const size_t WB2_OFF   = W_OFF + 256;
  const size_t W1T_OFF   = WB2_OFF + 4096;
  const size_t NEED      = W1T_OFF + 131072;

  if (ws_size < NEED) {  // deterministic fallback (correctness insurance)
    k_naive<<<B_N, 64, 0, stream>>>(bf, w_raw, W1, b1, gamma, beta, W2, b2, out);
    return;
  }
  char* ws = (char*)d_ws;
  uint4* W2T = (uint4*)ws;
  float* w_s = (float*)(ws + W_OFF);
  float* wb2 = (float*)(ws + WB2_OFF);
  uint4* W1T = (uint4*)(ws + W1T_OFF);

  k_prep<<<4, 128, 0, stream>>>(w_raw, b2, w_s, wb2, out + (size_t)B_N * E_N);
  k_w1t<<<64, 64, 0, stream>>>(W1, W1T);
  k_w2t<<<256, 256, 0, stream>>>(W2, W2T);
  k_fused<<<B_N / 64, 512, 0, stream>>>(bf, W1T, b1, gamma, beta, w_s, W2T, wb2, out);
}

// Round 5
// 393.492 us; speedup vs baseline: 1.2695x; 1.0995x over previous
//
#include <hip/hip_runtime.h>
#include <hip/hip_bf16.h>
#include <cstdint>

#define B_N 65536
#define F_N 64
#define L_N 32
#define E_N 512
// K = F*L = 2048, k-octs = 256

typedef short bf16x8 __attribute__((ext_vector_type(8)));
typedef float f32x4 __attribute__((ext_vector_type(4)));

// GELU via A&S 7.1.27 erf (|eps| <= 5e-4): 1 transcendental (rcp), no exp.
// R4 post-mortem: old A&S 7.1.26 form (exp+rcp, ~40cyc) was ~half the VALU.
__device__ __forceinline__ float gelu_fast(float v) {
  float z = fabsf(v) * 0.7071067811865476f;
  float p = fmaf(z, fmaf(z, fmaf(z, fmaf(z, 0.078108f, 0.000972f),
                                 0.230389f), 0.278393f), 1.0f);
  float p2 = p * p;
  float p4 = p2 * p2;
  float er = 1.0f - __builtin_amdgcn_rcpf(p4);  // erf(|z|)
  float half_er = copysignf(0.5f * er, v);
  return v * (0.5f + half_er);
}

// exact GELU (fallback kernel only)
__device__ __forceinline__ float gelu_exact(float v) {
  float z  = v * 0.7071067811865476f;
  float az = fabsf(z);
  float t  = __builtin_amdgcn_rcpf(fmaf(0.3275911f, az, 1.0f));
  float p  = t * fmaf(t, fmaf(t, fmaf(t, fmaf(t, 1.061405429f, -1.453152027f),
                                      1.421413741f), -0.284496736f), 0.254829592f);
  float e    = __expf(-z * z);
  float erfa = fmaf(-p, e, 1.0f);
  float er   = (z < 0.0f) ? -erfa : erfa;
  return v * fmaf(0.5f, er, 0.5f);
}

// ---------------- merged prep: wb2/out_tail (bb 0-1), W1T (bb 2-17),
// ---------------- W2T w-folded bf16 (bb 18-273). One launch. ---------------
__global__ __launch_bounds__(256) void k_pre(const float* __restrict__ w_raw,
                                             const float* __restrict__ b2,
                                             const float* __restrict__ W1,
                                             const float* __restrict__ W2,
                                             float* __restrict__ wb2,
                                             float* __restrict__ out_tail,
                                             uint4* __restrict__ W1T,
                                             uint4* __restrict__ W2T) {
  __shared__ float ls[64 * 65];
  int bb = blockIdx.x, tid = threadIdx.x;
  // redundant per-thread softmax (64-wide, cheap)
  float m = -1e30f;
  for (int i = 0; i < F_N; i++) m = fmaxf(m, w_raw[i]);
  float s = 0.f;
  for (int i = 0; i < F_N; i++) s += expf(w_raw[i] - m);
  float inv_s = 1.0f / s;

  if (bb < 2) {
    int e = bb * 256 + tid;
    float a = 0.f;
    for (int f = 0; f < F_N; f++)
      a = fmaf(expf(w_raw[f] - m) * inv_s, b2[f * E_N + e], a);
    wb2[e] = a;
    if (bb == 0 && tid < F_N) out_tail[tid] = expf(w_raw[tid] - m) * inv_s;
  } else if (bb < 18) {
    // W1T[(f*2+jt)*64+lane] = 8 bf16 { W1[f][quad*8+jj][jt*16+r16] }
    int f = (bb - 2) * 4 + (tid >> 6);
    int lane = tid & 63, quad = lane >> 4, r16 = lane & 15;
#pragma unroll
    for (int jt = 0; jt < 2; jt++) {
      union { __hip_bfloat162 p[4]; uint4 u; } pk;
#pragma unroll
      for (int d = 0; d < 4; d++) {
        float lo = W1[f * 1024 + (quad * 8 + 2 * d) * 32 + jt * 16 + r16];
        float hi = W1[f * 1024 + (quad * 8 + 2 * d + 1) * 32 + jt * 16 + r16];
        pk.p[d] = __float22bfloat162_rn(make_float2(lo, hi));
      }
      W1T[(f * 2 + jt) * 64 + lane] = pk.u;
    }
  } else {
    // W2T blocked [k_oct][e][8], rows pre-scaled by softmax w[f=k>>5]
    int blk = bb - 18;
    int kt = blk >> 3, et = blk & 7;
    int k0 = kt * 64, e0 = et * 64;
#pragma unroll
    for (int i = 0; i < 16; i++) {
      int idx = i * 256 + tid;
      int r = idx >> 6, c = idx & 63;
      float wrow = expf(w_raw[(k0 + r) >> 5] - m) * inv_s;
      ls[r * 65 + c] = W2[(size_t)(k0 + r) * E_N + e0 + c] * wrow;
    }
    __syncthreads();
#pragma unroll
    for (int i = 0; i < 2; i++) {
      int t = i * 256 + tid;
      int ko = t >> 6, e = t & 63;
      union { __hip_bfloat162 p[4]; uint4 u; } pk;
#pragma unroll
      for (int d = 0; d < 4; d++)
        pk.p[d] = __float22bfloat162_rn(make_float2(ls[(ko * 8 + 2 * d) * 65 + e],
                                                    ls[(ko * 8 + 2 * d + 1) * 65 + e]));
      W2T[(size_t)(kt * 8 + ko) * E_N + e0 + e] = pk.u;
    }
  }
}

// ---- enc chunk: wave's feature f=c*8+wave -> hwb (blocked [ko][b][8bf16]) --
__device__ __forceinline__ void enc_chunk(int c, int wave, int lane, int quad,
                                          int r16, const float* xs, uint4* hwb,
                                          const uint4* __restrict__ W1T,
                                          const float* __restrict__ b1,
                                          const float* __restrict__ gamma,
                                          const float* __restrict__ beta,
                                          float c_t, float phase) {
  int f = c * 8 + wave;
  bf16x8 a0 = __builtin_bit_cast(bf16x8, W1T[(f * 2 + 0) * 64 + lane]);
  bf16x8 a1 = __builtin_bit_cast(bf16x8, W1T[(f * 2 + 1) * 64 + lane]);
  f32x4 c0, c1;  // seed C with b1 (row j = jt*16 + quad*4 + rr)
  float gv[8], bev[8];
#pragma unroll
  for (int rr = 0; rr < 4; rr++) {
    c0[rr] = b1[f * 32 + quad * 4 + rr];
    c1[rr] = b1[f * 32 + 16 + quad * 4 + rr];
  }
#pragma unroll
  for (int q = 0; q < 8; q++) {
    int idx = f * 32 + (q >> 2) * 16 + quad * 4 + (q & 3);
    gv[q] = gamma[idx];
    bev[q] = beta[idx];
  }
#pragma unroll
  for (int bt = 0; bt < 4; bt++) {
    float x = xs[f * 65 + bt * 16 + r16];
    float v[8];
    float t = x * c_t;
#pragma unroll
    for (int jj = 0; jj < 8; jj++) {
      float y = t + phase;
      y = y - floorf(y);
      v[jj] = __builtin_amdgcn_sinf(y);
      t = t + t;
    }
    union { __hip_bfloat162 p[4]; bf16x8 r; } pk;
#pragma unroll
    for (int d = 0; d < 4; d++)
      pk.p[d] = __float22bfloat162_rn(make_float2(v[2 * d], v[2 * d + 1]));
    f32x4 e0 = __builtin_amdgcn_mfma_f32_16x16x32_bf16(a0, pk.r, c0, 0, 0, 0);
    f32x4 e1 = __builtin_amdgcn_mfma_f32_16x16x32_bf16(a1, pk.r, c1, 0, 0, 0);
    float h[8];
#pragma unroll
    for (int rr = 0; rr < 4; rr++) { h[rr] = e0[rr]; h[4 + rr] = e1[rr]; }
    float sum = 0.f;
#pragma unroll
    for (int q = 0; q < 8; q++) sum += h[q];
    sum += __shfl_xor(sum, 16);
    sum += __shfl_xor(sum, 32);
    float mu = sum * (1.0f / 32.0f);
    float var = 0.f;
#pragma unroll
    for (int q = 0; q < 8; q++) { h[q] -= mu; var = fmaf(h[q], h[q], var); }
    var += __shfl_xor(var, 16);
    var += __shfl_xor(var, 32);
    float rs = __builtin_amdgcn_rsqf(fmaf(var, (1.0f / 32.0f), 1e-5f));
#pragma unroll
    for (int q = 0; q < 8; q++) {
      float hn = fmaf(h[q] * rs, gv[q], bev[q]);
      h[q] = gelu_fast(hn);  // w[f] folded into W2T
    }
    int b_local = bt * 16 + r16;
#pragma unroll
    for (int jt = 0; jt < 2; jt++) {
      union { __hip_bfloat162 p[2]; uint2 u; } pw;
      pw.p[0] = __float22bfloat162_rn(make_float2(h[jt * 4 + 0], h[jt * 4 + 1]));
      pw.p[1] = __float22bfloat162_rn(make_float2(h[jt * 4 + 2], h[jt * 4 + 3]));
      int ko_local = wave * 4 + jt * 2 + (quad >> 1);
      *(uint2*)((char*)hwb + ((size_t)(ko_local * 64 + b_local) * 16 +
                              (quad & 1) * 8)) = pw.u;
    }
  }
}

// ---- gemm chunk: acc += hwb(64b x 256k) @ W2T[c](256k x 64n strip) --------
__device__ __forceinline__ void gemm_chunk(int c, int n_base, int quad, int r16,
                                           const uint4* hwb,
                                           const uint4* __restrict__ W2T,
                                           f32x4 (&acc)[4][4]) {
#pragma unroll
  for (int s = 0; s < 8; s++) {
    bf16x8 af[4], bfr[4];
#pragma unroll
    for (int nt = 0; nt < 4; nt++)
      bfr[nt] = __builtin_bit_cast(
          bf16x8, W2T[(size_t)(c * 32 + s * 4 + quad) * E_N + n_base + nt * 16 + r16]);
#pragma unroll
    for (int mt = 0; mt < 4; mt++)
      af[mt] = __builtin_bit_cast(bf16x8, hwb[(s * 4 + quad) * 64 + mt * 16 + r16]);
#pragma unroll
    for (int mt = 0; mt < 4; mt++)
#pragma unroll
      for (int nt = 0; nt < 4; nt++)
        acc[mt][nt] = __builtin_amdgcn_mfma_f32_16x16x32_bf16(af[mt], bfr[nt],
                                                              acc[mt][nt], 0, 0, 0);
  }
}

// ---------------- FUSED, software-pipelined -------------------------------
// Double-buffered hw LDS: gemm(c) and enc(c+1) share one barrier-free region
// so the scheduler co-issues MFMA (gemm) with VALU (enc). 1 block/CU.
__global__ __launch_bounds__(512, 2) void k_fused(const float* __restrict__ bf,
                                                  const uint4* __restrict__ W1T,
                                                  const float* __restrict__ b1,
                                                  const float* __restrict__ gamma,
                                                  const float* __restrict__ beta,
                                                  const uint4* __restrict__ W2T,
                                                  const float* __restrict__ wb2,
                                                  float* __restrict__ out) {
  __shared__ float xs[64 * 65];     // x transposed [f][b]
  __shared__ uint4 hwA[32 * 64];    // Hw chunk buffers (32 KB each)
  __shared__ uint4 hwB[32 * 64];
  int tid = threadIdx.x;
  int b0 = blockIdx.x * 64;
#pragma unroll
  for (int i = 0; i < 8; i++) {
    int idx = i * 512 + tid;
    xs[(idx & 63) * 65 + (idx >> 6)] = bf[(size_t)b0 * F_N + idx];
  }
  int wave = tid >> 6, lane = tid & 63;
  int quad = lane >> 4, r16 = lane & 15;
  float c_t   = 0.015915494309189535f * ((quad & 1) ? 256.0f : 1.0f);
  float phase = (quad >= 2) ? 0.25f : 0.0f;
  int n_base = wave * 64;

  f32x4 acc[4][4];
  f32x4 zero = {0.f, 0.f, 0.f, 0.f};
#pragma unroll
  for (int i = 0; i < 4; i++)
#pragma unroll
    for (int j = 0; j < 4; j++) acc[i][j] = zero;

  __syncthreads();  // xs visible
  enc_chunk(0, wave, lane, quad, r16, xs, hwA, W1T, b1, gamma, beta, c_t, phase);
  __syncthreads();  // hwA visible

  for (int cc = 0; cc < 4; ++cc) {
    // gemm(2cc, A) || enc(2cc+1 -> B)
    gemm_chunk(cc * 2, n_base, quad, r16, hwA, W2T, acc);
    enc_chunk(cc * 2 + 1, wave, lane, quad, r16, xs, hwB, W1T, b1, gamma, beta,
              c_t, phase);
    __syncthreads();  // hwB visible; hwA reads done
    // gemm(2cc+1, B) || enc(2cc+2 -> A)
    gemm_chunk(cc * 2 + 1, n_base, quad, r16, hwB, W2T, acc);
    if (cc < 3)
      enc_chunk(cc * 2 + 2, wave, lane, quad, r16, xs, hwA, W1T, b1, gamma, beta,
                c_t, phase);
    __syncthreads();
  }

  // epilogue: C/D layout col=n (r16), row=m (quad*4+rr); add wb2 bias
#pragma unroll
  for (int nt = 0; nt < 4; nt++) {
    int n = n_base + nt * 16 + r16;
    float bias = wb2[n];
#pragma unroll
    for (int mt = 0; mt < 4; mt++) {
#pragma unroll
      for (int rr = 0; rr < 4; rr++) {
        int m = b0 + mt * 16 + quad * 4 + rr;
        out[(size_t)m * E_N + n] = acc[mt][nt][rr] + bias;
      }
    }
  }
}

// ---------------- correctness fallback if ws_size too small ----------------
__global__ __launch_bounds__(64) void k_naive(const float* __restrict__ bf,
                                              const float* __restrict__ w_raw,
                                              const float* __restrict__ W1,
                                              const float* __restrict__ b1,
                                              const float* __restrict__ gamma,
                                              const float* __restrict__ beta,
                                              const float* __restrict__ W2,
                                              const float* __restrict__ b2,
                                              float* __restrict__ out) {
  int b = blockIdx.x;
  int lane = threadIdx.x;
  float m = -1e30f;
  for (int i = 0; i < F_N; i++) m = fmaxf(m, w_raw[i]);
  float s = 0.f;
  for (int i = 0; i < F_N; i++) s += expf(w_raw[i] - m);
  float inv_s = 1.0f / s;
  float acc[8];
#pragma unroll
  for (int r = 0; r < 8; r++) acc[r] = 0.f;
  __shared__ float hs[32];
  for (int f = 0; f < F_N; f++) {
    float wf = expf(w_raw[f] - m) * inv_s;
    __syncthreads();
    if (lane < 32) {
      float x = bf[(size_t)b * F_N + f];
      float t = x * 0.015915494309189535f;
      float h = b1[f * 32 + lane];
#pragma unroll
      for (int i = 0; i < 16; i++) {
        float y = t - floorf(t);
        h = fmaf(__builtin_amdgcn_sinf(y), W1[f * 1024 + i * 32 + lane], h);
        h = fmaf(__builtin_amdgcn_cosf(y), W1[f * 1024 + 512 + i * 32 + lane], h);
        t = t + t;
      }
      float sum = h;
#pragma unroll
      for (int msk = 1; msk < 32; msk <<= 1) sum += __shfl_xor(sum, msk, 64);
      float mu = sum * (1.0f / 32.0f);
      float d = h - mu;
      float sq = d * d;
#pragma unroll
      for (int msk = 1; msk < 32; msk <<= 1) sq += __shfl_xor(sq, msk, 64);
      float rs = __builtin_amdgcn_rsqf(fmaf(sq, (1.0f / 32.0f), 1e-5f));
      float hn = fmaf(d * rs, gamma[f * 32 + lane], beta[f * 32 + lane]);
      hs[lane] = gelu_exact(hn) * wf;
    }
    __syncthreads();
#pragma unroll
    for (int r = 0; r < 8; r++) {
      int e = r * 64 + lane;
      float a = fmaf(wf, b2[f * E_N + e], acc[r]);
      for (int j = 0; j < 32; j++)
        a = fmaf(hs[j], W2[(size_t)(f * 32 + j) * E_N + e], a);
      acc[r] = a;
    }
  }
#pragma unroll
  for (int r = 0; r < 8; r++) out[(size_t)b * E_N + r * 64 + lane] = acc[r];
  if (b == 0) out[(size_t)B_N * E_N + lane] = expf(w_raw[lane] - m) * inv_s;
}

extern "C" void kernel_launch(void* const* d_in, const int* in_sizes, int n_in,
                              void* d_out, int out_size, void* d_ws, size_t ws_size,
                              hipStream_t stream) {
  const float* bf    = (const float*)d_in[0];
  const float* w_raw = (const float*)d_in[1];
  const float* W1    = (const float*)d_in[2];
  const float* b1    = (const float*)d_in[3];
  const float* gamma = (const float*)d_in[4];
  const float* beta  = (const float*)d_in[5];
  const float* W2    = (const float*)d_in[6];
  const float* b2    = (const float*)d_in[7];
  float* out = (float*)d_out;

  const size_t W2T_BYTES = (size_t)256 * E_N * 16;  // 2 MB
  const size_t W_OFF     = W2T_BYTES;
  const size_t WB2_OFF   = W_OFF + 256;
  const size_t W1T_OFF   = WB2_OFF + 4096;
  const size_t NEED      = W1T_OFF + 131072;

  if (ws_size < NEED) {  // deterministic fallback (correctness insurance)
    k_naive<<<B_N, 64, 0, stream>>>(bf, w_raw, W1, b1, gamma, beta, W2, b2, out);
    return;
  }
  char* ws = (char*)d_ws;
  uint4* W2T = (uint4*)ws;
  float* wb2 = (float*)(ws + WB2_OFF);
  uint4* W1T = (uint4*)(ws + W1T_OFF);

  k_pre<<<274, 256, 0, stream>>>(w_raw, b2, W1, W2, wb2,
                                 out + (size_t)B_N * E_N, W1T, W2T);
  k_fused<<<B_N / 64, 512, 0, stream>>>(bf, W1T, b1, gamma, beta, W2T, wb2, out);
}